// Round 7
// baseline (166.910 us; speedup 1.0000x reference)
//
#include <hip/hip_runtime.h>

#define N_NODES 100000
#define N_EDGES 2000000

typedef __bf16 bf16x8 __attribute__((ext_vector_type(8)));
typedef float f32x4 __attribute__((ext_vector_type(4)));
typedef float f32x16 __attribute__((ext_vector_type(16)));
typedef unsigned short u16x2 __attribute__((ext_vector_type(2)));

#define AS1 __attribute__((address_space(1)))
#define AS3 __attribute__((address_space(3)))

__device__ __forceinline__ unsigned f2bf_rne(float f) {
  unsigned u = __builtin_bit_cast(unsigned, f);
  u += 0x7FFFu + ((u >> 16) & 1u);
  return u >> 16;
}

// Pack two NON-NEGATIVE f32 into bf16x2, round-half-up.
__device__ __forceinline__ unsigned pack_rhu(float lo, float hi) {
  unsigned ulo = __builtin_bit_cast(unsigned, lo) + 0x8000u;
  unsigned uhi = __builtin_bit_cast(unsigned, hi) + 0x8000u;
  return __builtin_amdgcn_perm(uhi, ulo, 0x07060302u);
}

// Packed u16 max/min: for NON-NEGATIVE bf16 (post-ReLU), the 16-bit pattern
// is monotone in the float value, so integer max/min == float max/min.
// Emits v_pk_max_u16 / v_pk_min_u16.
__device__ __forceinline__ unsigned pk_max_u16(unsigned a, unsigned b) {
  u16x2 r = __builtin_elementwise_max(__builtin_bit_cast(u16x2, a),
                                      __builtin_bit_cast(u16x2, b));
  return __builtin_bit_cast(unsigned, r);
}
__device__ __forceinline__ unsigned pk_min_u16(unsigned a, unsigned b) {
  u16x2 r = __builtin_elementwise_min(__builtin_bit_cast(u16x2, a),
                                      __builtin_bit_cast(u16x2, b));
  return __builtin_bit_cast(unsigned, r);
}

// ---------------------------------------------------------------------------
// Node MLP via MFMA, grid-stride (proven version, unchanged).
// ---------------------------------------------------------------------------
__global__ __launch_bounds__(64, 1) void node_mfma_kernel(
    const float* __restrict__ X, const float* __restrict__ W1,
    const float* __restrict__ b1, const float* __restrict__ W2,
    const float* __restrict__ b2, unsigned short* __restrict__ H) {
  const int lane = threadIdx.x;
  const int l15 = lane & 15;
  const int quad = lane >> 4;

  float w1v[2][4][8], b1v[2][8];
#pragma unroll
  for (int c = 0; c < 2; ++c)
#pragma unroll
    for (int j = 0; j < 8; ++j) {
      int col = c * 32 + quad * 8 + j;
      b1v[c][j] = b1[col];
#pragma unroll
      for (int d = 0; d < 4; ++d) w1v[c][d][j] = W1[d * 64 + col];
    }

  uint4 afr[2][4];
#pragma unroll
  for (int c = 0; c < 2; ++c)
#pragma unroll
    for (int mt = 0; mt < 4; ++mt) {
      unsigned w[4];
#pragma unroll
      for (int p = 0; p < 4; ++p) {
        int k = c * 32 + quad * 8 + 2 * p;
        unsigned lo = f2bf_rne(W2[k * 64 + mt * 16 + l15]);
        unsigned hi = f2bf_rne(W2[(k + 1) * 64 + mt * 16 + l15]);
        w[p] = lo | (hi << 16);
      }
      afr[c][mt] = make_uint4(w[0], w[1], w[2], w[3]);
    }
  float b2v[16];
#pragma unroll
  for (int mt = 0; mt < 4; ++mt)
#pragma unroll
    for (int r = 0; r < 4; ++r) b2v[mt * 4 + r] = b2[mt * 16 + quad * 4 + r];

  const int ntiles = N_NODES / 16;  // 6250
  for (int tile = blockIdx.x; tile < ntiles; tile += gridDim.x) {
    float4 xv = ((const float4*)X)[tile * 16 + l15];

    uint4 bfr[2];
#pragma unroll
    for (int c = 0; c < 2; ++c) {
      unsigned w[4];
#pragma unroll
      for (int p = 0; p < 4; ++p) {
        float h0 = fmaxf(b1v[c][2 * p] + xv.x * w1v[c][0][2 * p] +
                             xv.y * w1v[c][1][2 * p] + xv.z * w1v[c][2][2 * p] +
                             xv.w * w1v[c][3][2 * p],
                         0.f);
        float h1 = fmaxf(b1v[c][2 * p + 1] + xv.x * w1v[c][0][2 * p + 1] +
                             xv.y * w1v[c][1][2 * p + 1] +
                             xv.z * w1v[c][2][2 * p + 1] +
                             xv.w * w1v[c][3][2 * p + 1],
                         0.f);
        w[p] = pack_rhu(h0, h1);
      }
      bfr[c] = make_uint4(w[0], w[1], w[2], w[3]);
    }

    f32x4 acc[4];
#pragma unroll
    for (int mt = 0; mt < 4; ++mt) acc[mt] = (f32x4){0.f, 0.f, 0.f, 0.f};
#pragma unroll
    for (int c = 0; c < 2; ++c)
#pragma unroll
      for (int mt = 0; mt < 4; ++mt)
        acc[mt] = __builtin_amdgcn_mfma_f32_16x16x32_bf16(
            __builtin_bit_cast(bf16x8, afr[c][mt]),
            __builtin_bit_cast(bf16x8, bfr[c]), acc[mt], 0, 0, 0);

    unsigned short* hrow = H + (tile * 16 + l15) * 64;
#pragma unroll
    for (int mt = 0; mt < 4; ++mt) {
      unsigned lo = pack_rhu(fmaxf(acc[mt][0] + b2v[mt * 4 + 0], 0.f),
                             fmaxf(acc[mt][1] + b2v[mt * 4 + 1], 0.f));
      unsigned hi = pack_rhu(fmaxf(acc[mt][2] + b2v[mt * 4 + 2], 0.f),
                             fmaxf(acc[mt][3] + b2v[mt * 4 + 3], 0.f));
      *(uint2*)(hrow + mt * 16 + quad * 4) = make_uint2(lo, hi);
    }
  }
}

// ---------------------------------------------------------------------------
// Edge MLP v6: round-0's proven LDS-staged coalesced gathers + double buffer
// (79us structure), with the absdiff VALU replaced by the max/min-in-MFMA
// transform:
//   |hu-hv| = max(hu,hv) - min(hu,hv)  (elementwise, hu,hv >= 0 post-ReLU)
//   |hu-hv| @ Ww = max @ Ww + (-min) @ Ww
// Packed integer v_pk_max/min_u16 give float max/min on non-negative bf16
// patterns; negation of min is a sign-bit OR. 176 VALU ops/tile -> 48, the
// subtraction happens exactly in the f32 MFMA accumulator (one LESS bf16
// rounding than before), and the Ww A-frags are REUSED for both feeds (no
// new weight registers). MFMA count 26 -> 34 per tile (MfmaUtil has room).
// We2 epilogue constants move to a 256B LDS broadcast (-32 VGPRs) so peak
// pressure stays ~240 <= 256 at (256,2).
//
// Staging/vmcnt schedule is byte-identical to round-0: two 8KB buffers per
// wave, refill for tile t+1 issued at top of tile t's compute, partial
// s_waitcnt vmcnt(5) (8 gathers retired; 4 pairs-loads + 1 store younger).
// ---------------------------------------------------------------------------
__global__ __launch_bounds__(256, 2) void edge_mlp_kernel(
    const unsigned short* __restrict__ H, const int* __restrict__ pairs,
    const float* __restrict__ We1, const float* __restrict__ be1,
    const float* __restrict__ We2, const float* __restrict__ be2,
    float* __restrict__ out) {
  __shared__ uint4 gbuf[4][2][512];  // [wave][buf][rows]: 64 KB
  __shared__ uint4 scratch[64];      // 1 KB dummy-gather landing pad
  __shared__ float lds_c[64];        // We2, broadcast in epilogue
  const int tid = threadIdx.x;
  const int lane = tid & 63;
  const int n = lane & 31;       // edge within tile (readback role)
  const int half = lane >> 5;    // k-half (readback role)
  const int wave = tid >> 6;
  const int rowsel = lane >> 3;  // loader role: row within 8-row group
  const int swzc = (lane & 7) ^ rowsel;  // global 16B chunk to fetch

  if (tid < 64) lds_c[tid] = We2[tid];

  // We1^T A-frags in registers: afr[c][mt] elem j =
  //   c<12 : We1[(c*16+half*8+j)*64 + mt*32+n]   (bf16 RNE packed)
  //   c==12: bias chunk A13[:,0]=be1 -> elem0 = be1[col] if half==0
  uint4 afr[13][2];
#pragma unroll
  for (int c = 0; c < 12; ++c)
#pragma unroll
    for (int mt = 0; mt < 2; ++mt) {
      int col = mt * 32 + n;
      int kb = c * 16 + half * 8;
      unsigned w[4];
#pragma unroll
      for (int p = 0; p < 4; ++p)
        w[p] = f2bf_rne(We1[(kb + 2 * p) * 64 + col]) |
               (f2bf_rne(We1[(kb + 2 * p + 1) * 64 + col]) << 16);
      afr[c][mt] = make_uint4(w[0], w[1], w[2], w[3]);
    }
#pragma unroll
  for (int mt = 0; mt < 2; ++mt)
    afr[12][mt] =
        make_uint4((half == 0) ? f2bf_rne(be1[mt * 32 + n]) : 0u, 0u, 0u, 0u);

  // B-frag for the bias chunk: B13[0][n]=1.0.
  const uint4 b13u = make_uint4((half == 0) ? 0x00003F80u : 0u, 0u, 0u, 0u);
  const float be2v = be2[0];

  uint4* const bufA = &gbuf[wave][0][0];
  uint4* const bufB = &gbuf[wave][1][0];
  int rbo[4];
#pragma unroll
  for (int c = 0; c < 4; ++c) rbo[c] = n * 8 + ((2 * c + half) ^ (n & 7));

  const int wid = blockIdx.x * 4 + wave;
  const int nw = gridDim.x * 4;  // 2048
  const int ntiles = N_EDGES / 32;
  const int last = ntiles - 1;
  const int2* pairs2 = (const int2*)pairs;

  // lds_c visible to all waves before the loop; also drains all prior vmem
  // so the prologue's vmcnt accounting starts clean.
  __syncthreads();

  // Issue the 8 row-group gathers for one tile into buffer `dst`.
  auto issue_gathers = [&](uint4* dst, const int2* prs) {
#pragma unroll
    for (int k = 0; k < 4; ++k) {
      const AS1 unsigned* gu =
          (const AS1 unsigned*)(H + (size_t)prs[k].x * 64) + swzc * 4;
      const AS1 unsigned* gv =
          (const AS1 unsigned*)(H + (size_t)prs[k].y * 64) + swzc * 4;
      __builtin_amdgcn_global_load_lds(gu, (AS3 unsigned*)(dst + k * 64), 16,
                                       0, 0);
      __builtin_amdgcn_global_load_lds(
          gv, (AS3 unsigned*)(dst + 256 + k * 64), 16, 0, 0);
    }
  };

  // Prologue: gathers(t0)->A [8]; pr=pairs(t1) [4]; dummy [1] => 13
  // outstanding, so iter0's vmcnt(5) retires exactly the 8 t0-gathers.
  int2 pr[4];
  {
#pragma unroll
    for (int k = 0; k < 4; ++k) pr[k] = pairs2[wid * 32 + k * 8 + rowsel];
    issue_gathers(bufA, pr);
    int t1 = wid + nw <= last ? wid + nw : last;
#pragma unroll
    for (int k = 0; k < 4; ++k) pr[k] = pairs2[t1 * 32 + k * 8 + rowsel];
    __builtin_amdgcn_global_load_lds((const AS1 unsigned*)H,
                                     (AS3 unsigned*)scratch, 16, 0, 0);
  }

  // One tile: consume CONS (tile tc), refill FILL (tile tc+nw, pairs in pr),
  // reload pr for tile tc+2nw, epilogue store.
  auto body = [&](int tc, uint4* CONS, uint4* FILL) {
    __builtin_amdgcn_sched_barrier(0);
    __builtin_amdgcn_s_waitcnt(0x0F75);  // vmcnt(5): this tile's rows landed
    __builtin_amdgcn_sched_barrier(0);

    issue_gathers(FILL, pr);  // tile tc+nw, one full compute ahead of use
    __builtin_amdgcn_sched_barrier(0);  // pin: gathers before pairs loads
    {
      int tn = tc + 2 * nw <= last ? tc + 2 * nw : last;
#pragma unroll
      for (int k = 0; k < 4; ++k) pr[k] = pairs2[tn * 32 + k * 8 + rowsel];
    }

    const int t = tc <= last ? tc : last;  // tail: recompute last (idempotent)
    uint4 hu[4], hv[4];
#pragma unroll
    for (int c = 0; c < 4; ++c) {
      hu[c] = CONS[rbo[c]];
      hv[c] = CONS[256 + rbo[c]];
    }
    // Packed elementwise max / (negated) min of the non-negative bf16 rows.
    uint4 pmx[4], pmn[4];
#pragma unroll
    for (int c = 0; c < 4; ++c) {
      pmx[c].x = pk_max_u16(hu[c].x, hv[c].x);
      pmx[c].y = pk_max_u16(hu[c].y, hv[c].y);
      pmx[c].z = pk_max_u16(hu[c].z, hv[c].z);
      pmx[c].w = pk_max_u16(hu[c].w, hv[c].w);
      pmn[c].x = pk_min_u16(hu[c].x, hv[c].x) | 0x80008000u;
      pmn[c].y = pk_min_u16(hu[c].y, hv[c].y) | 0x80008000u;
      pmn[c].z = pk_min_u16(hu[c].z, hv[c].z) | 0x80008000u;
      pmn[c].w = pk_min_u16(hu[c].w, hv[c].w) | 0x80008000u;
    }

    f32x16 acc[2];
    acc[0] = (f32x16)(0.f);
    acc[1] = (f32x16)(0.f);
#pragma unroll
    for (int c = 0; c < 4; ++c) {
      const bf16x8 b = __builtin_bit_cast(bf16x8, hu[c]);
#pragma unroll
      for (int mt = 0; mt < 2; ++mt)
        acc[mt] = __builtin_amdgcn_mfma_f32_32x32x16_bf16(
            __builtin_bit_cast(bf16x8, afr[c][mt]), b, acc[mt], 0, 0, 0);
    }
#pragma unroll
    for (int c = 0; c < 4; ++c) {
      const bf16x8 b = __builtin_bit_cast(bf16x8, hv[c]);
#pragma unroll
      for (int mt = 0; mt < 2; ++mt)
        acc[mt] = __builtin_amdgcn_mfma_f32_32x32x16_bf16(
            __builtin_bit_cast(bf16x8, afr[4 + c][mt]), b, acc[mt], 0, 0, 0);
    }
    // |hu-hv| @ Ww  ==  pmx @ Ww + (-pmn) @ Ww  (same A-frags, exact in f32).
#pragma unroll
    for (int c = 0; c < 4; ++c) {
      const bf16x8 b = __builtin_bit_cast(bf16x8, pmx[c]);
#pragma unroll
      for (int mt = 0; mt < 2; ++mt)
        acc[mt] = __builtin_amdgcn_mfma_f32_32x32x16_bf16(
            __builtin_bit_cast(bf16x8, afr[8 + c][mt]), b, acc[mt], 0, 0, 0);
    }
#pragma unroll
    for (int c = 0; c < 4; ++c) {
      const bf16x8 b = __builtin_bit_cast(bf16x8, pmn[c]);
#pragma unroll
      for (int mt = 0; mt < 2; ++mt)
        acc[mt] = __builtin_amdgcn_mfma_f32_32x32x16_bf16(
            __builtin_bit_cast(bf16x8, afr[8 + c][mt]), b, acc[mt], 0, 0, 0);
    }
#pragma unroll
    for (int mt = 0; mt < 2; ++mt)
      acc[mt] = __builtin_amdgcn_mfma_f32_32x32x16_bf16(
          __builtin_bit_cast(bf16x8, afr[12][mt]),
          __builtin_bit_cast(bf16x8, b13u), acc[mt], 0, 0, 0);

    // Epilogue: relu + We2 dot (We2 broadcast from LDS).
    // acc[mt][4g+q] -> row o = mt*32 + q + 8g + 4*half.
    float s = 0.f;
#pragma unroll
    for (int mt = 0; mt < 2; ++mt)
#pragma unroll
      for (int g = 0; g < 4; ++g) {
        const float4 ew = *(const float4*)&lds_c[mt * 32 + g * 8 + 4 * half];
        s += fmaxf(acc[mt][4 * g + 0], 0.f) * ew.x;
        s += fmaxf(acc[mt][4 * g + 1], 0.f) * ew.y;
        s += fmaxf(acc[mt][4 * g + 2], 0.f) * ew.z;
        s += fmaxf(acc[mt][4 * g + 3], 0.f) * ew.w;
      }
    s += __shfl_xor(s, 32);
    if (half == 0) out[t * 32 + n] = s + be2v;
  };

  for (int t = wid; t < ntiles; t += 2 * nw) {
    body(t, bufA, bufB);
    body(t + nw, bufB, bufA);
  }
}

extern "C" void kernel_launch(void* const* d_in, const int* in_sizes, int n_in,
                              void* d_out, int out_size, void* d_ws,
                              size_t ws_size, hipStream_t stream) {
  const float* X = (const float*)d_in[0];
  const int* pairs = (const int*)d_in[1];
  const float* W1 = (const float*)d_in[2];
  const float* b1 = (const float*)d_in[3];
  const float* W2 = (const float*)d_in[4];
  const float* b2 = (const float*)d_in[5];
  const float* We1 = (const float*)d_in[6];
  const float* be1 = (const float*)d_in[7];
  const float* We2 = (const float*)d_in[8];
  const float* be2 = (const float*)d_in[9];
  float* out = (float*)d_out;
  unsigned short* H = (unsigned short*)d_ws;  // 100000*64 bf16 = 12.8 MB

  node_mfma_kernel<<<1024, 64, 0, stream>>>(X, W1, b1, W2, b2, H);
  // 65.25 KB LDS/block -> 2 blocks/CU, 8 waves/CU, 2 waves/SIMD (as r0).
  edge_mlp_kernel<<<512, 256, 0, stream>>>(H, pairs, We1, be1, We2, be2, out);
}

// Round 8
// 156.567 us; speedup vs baseline: 1.0661x; 1.0661x over previous
//
#include <hip/hip_runtime.h>

#define N_NODES 100000
#define N_EDGES 2000000

typedef __bf16 bf16x8 __attribute__((ext_vector_type(8)));
typedef float f32x4 __attribute__((ext_vector_type(4)));
typedef float f32x16 __attribute__((ext_vector_type(16)));

#define AS1 __attribute__((address_space(1)))
#define AS3 __attribute__((address_space(3)))

struct TrueTag { static constexpr bool value = true; };
struct FalseTag { static constexpr bool value = false; };

__device__ __forceinline__ unsigned f2bf_rne(float f) {
  unsigned u = __builtin_bit_cast(unsigned, f);
  u += 0x7FFFu + ((u >> 16) & 1u);
  return u >> 16;
}

// Pack two NON-NEGATIVE f32 into bf16x2, round-half-up.
__device__ __forceinline__ unsigned pack_rhu(float lo, float hi) {
  unsigned ulo = __builtin_bit_cast(unsigned, lo) + 0x8000u;
  unsigned uhi = __builtin_bit_cast(unsigned, hi) + 0x8000u;
  return __builtin_amdgcn_perm(uhi, ulo, 0x07060302u);
}

// |a-b| on a packed bf16 pair -> packed bf16 pair.
__device__ __forceinline__ unsigned absdiff_pack(unsigned a, unsigned b) {
  float alo = __builtin_bit_cast(float, a << 16);
  float ahi = __builtin_bit_cast(float, a & 0xFFFF0000u);
  float blo = __builtin_bit_cast(float, b << 16);
  float bhi = __builtin_bit_cast(float, b & 0xFFFF0000u);
  return pack_rhu(fabsf(alo - blo), fabsf(ahi - bhi));
}

// ---------------------------------------------------------------------------
// Node MLP via MFMA, grid-stride (proven version, unchanged).
// ---------------------------------------------------------------------------
__global__ __launch_bounds__(64, 1) void node_mfma_kernel(
    const float* __restrict__ X, const float* __restrict__ W1,
    const float* __restrict__ b1, const float* __restrict__ W2,
    const float* __restrict__ b2, unsigned short* __restrict__ H) {
  const int lane = threadIdx.x;
  const int l15 = lane & 15;
  const int quad = lane >> 4;

  float w1v[2][4][8], b1v[2][8];
#pragma unroll
  for (int c = 0; c < 2; ++c)
#pragma unroll
    for (int j = 0; j < 8; ++j) {
      int col = c * 32 + quad * 8 + j;
      b1v[c][j] = b1[col];
#pragma unroll
      for (int d = 0; d < 4; ++d) w1v[c][d][j] = W1[d * 64 + col];
    }

  uint4 afr[2][4];
#pragma unroll
  for (int c = 0; c < 2; ++c)
#pragma unroll
    for (int mt = 0; mt < 4; ++mt) {
      unsigned w[4];
#pragma unroll
      for (int p = 0; p < 4; ++p) {
        int k = c * 32 + quad * 8 + 2 * p;
        unsigned lo = f2bf_rne(W2[k * 64 + mt * 16 + l15]);
        unsigned hi = f2bf_rne(W2[(k + 1) * 64 + mt * 16 + l15]);
        w[p] = lo | (hi << 16);
      }
      afr[c][mt] = make_uint4(w[0], w[1], w[2], w[3]);
    }
  float b2v[16];
#pragma unroll
  for (int mt = 0; mt < 4; ++mt)
#pragma unroll
    for (int r = 0; r < 4; ++r) b2v[mt * 4 + r] = b2[mt * 16 + quad * 4 + r];

  const int ntiles = N_NODES / 16;  // 6250
  for (int tile = blockIdx.x; tile < ntiles; tile += gridDim.x) {
    float4 xv = ((const float4*)X)[tile * 16 + l15];

    uint4 bfr[2];
#pragma unroll
    for (int c = 0; c < 2; ++c) {
      unsigned w[4];
#pragma unroll
      for (int p = 0; p < 4; ++p) {
        float h0 = fmaxf(b1v[c][2 * p] + xv.x * w1v[c][0][2 * p] +
                             xv.y * w1v[c][1][2 * p] + xv.z * w1v[c][2][2 * p] +
                             xv.w * w1v[c][3][2 * p],
                         0.f);
        float h1 = fmaxf(b1v[c][2 * p + 1] + xv.x * w1v[c][0][2 * p + 1] +
                             xv.y * w1v[c][1][2 * p + 1] +
                             xv.z * w1v[c][2][2 * p + 1] +
                             xv.w * w1v[c][3][2 * p + 1],
                         0.f);
        w[p] = pack_rhu(h0, h1);
      }
      bfr[c] = make_uint4(w[0], w[1], w[2], w[3]);
    }

    f32x4 acc[4];
#pragma unroll
    for (int mt = 0; mt < 4; ++mt) acc[mt] = (f32x4){0.f, 0.f, 0.f, 0.f};
#pragma unroll
    for (int c = 0; c < 2; ++c)
#pragma unroll
      for (int mt = 0; mt < 4; ++mt)
        acc[mt] = __builtin_amdgcn_mfma_f32_16x16x32_bf16(
            __builtin_bit_cast(bf16x8, afr[c][mt]),
            __builtin_bit_cast(bf16x8, bfr[c]), acc[mt], 0, 0, 0);

    unsigned short* hrow = H + (tile * 16 + l15) * 64;
#pragma unroll
    for (int mt = 0; mt < 4; ++mt) {
      unsigned lo = pack_rhu(fmaxf(acc[mt][0] + b2v[mt * 4 + 0], 0.f),
                             fmaxf(acc[mt][1] + b2v[mt * 4 + 1], 0.f));
      unsigned hi = pack_rhu(fmaxf(acc[mt][2] + b2v[mt * 4 + 2], 0.f),
                             fmaxf(acc[mt][3] + b2v[mt * 4 + 3], 0.f));
      *(uint2*)(hrow + mt * 16 + quad * 4) = make_uint2(lo, hi);
    }
  }
}

// ---------------------------------------------------------------------------
// Edge MLP v7: r0's staged coalesced gathers at 3 waves/SIMD (12 waves/CU).
//
// Diagnosis across r0..r7: every 8-waves/CU config lands 79-95us with all
// pipes <=35-50% busy -> latency-bound, occupancy is the binding constraint.
// r5's 12-waves/CU attempt was poisoned by per-lane scattered gathers (8x TA
// line-touches). This version keeps r0's coalesced global_load_lds staging
// and gets to 12 waves/CU by:
//  - SINGLE 8KB buffer/wave (32KB/block). The refill for t+nw is issued
//    right after this tile's rows are read to regs (lgkm fence); exposed
//    gather latency is covered by 3 waves/SIMD.
//  - We1^T split: chunks 0..5 in regs (48), chunks 6..11 in 12KB LDS read
//    just-in-time per MFMA (r5-proven pattern), bias chunk as 2 regs.
//    Peak regs ~160 <= 168 at (256,3).
//  - absdiff VALU math (r0-proven; pk-minmax regressed at r7).
//  - iter-0 peel: vmcnt(4) first tile, vmcnt(5) steady (8 gathers + 4 pairs
//    + 1 store in flight), no dummy-load scratch needed.
// LDS total 44.3KB -> 3 blocks/CU. Grid 768 = exactly resident.
// ---------------------------------------------------------------------------
__global__ __launch_bounds__(256, 3) void edge_mlp_kernel(
    const unsigned short* __restrict__ H, const int* __restrict__ pairs,
    const float* __restrict__ We1, const float* __restrict__ be1,
    const float* __restrict__ We2, const float* __restrict__ be2,
    float* __restrict__ out) {
  __shared__ uint4 gbuf[4][512];      // 32 KB: one 8KB row buffer per wave
  __shared__ uint4 lds_w6[6][2][64];  // 12 KB: We1^T chunks 6..11
  __shared__ float lds_c[64];         // 256 B: We2 (epilogue broadcast)

  const int tid = threadIdx.x;
  const int lane = tid & 63;
  const int n = lane & 31;       // edge within tile (readback role)
  const int half = lane >> 5;    // k-half (readback role)
  const int wave = tid >> 6;
  const int rowsel = lane >> 3;  // loader role: row within 8-row group
  const int swzc = (lane & 7) ^ rowsel;  // global 16B chunk to fetch

  if (tid < 64) lds_c[tid] = We2[tid];

  // Stage We1^T chunks 6..11 to LDS cooperatively (wave w fills 3 items).
  // lds_w6[c-6][mt][lane] elem j = bf16(We1[(c*16+half*8+j)*64 + mt*32+n]).
#pragma unroll
  for (int i = 0; i < 3; ++i) {
    const int idx = wave * 3 + i;  // 0..11
    const int c = 6 + (idx >> 1);
    const int mt = idx & 1;
    const int col = mt * 32 + n;
    const int kb = c * 16 + half * 8;
    unsigned w[4];
#pragma unroll
    for (int p = 0; p < 4; ++p)
      w[p] = f2bf_rne(We1[(kb + 2 * p) * 64 + col]) |
             (f2bf_rne(We1[(kb + 2 * p + 1) * 64 + col]) << 16);
    lds_w6[c - 6][mt][lane] = make_uint4(w[0], w[1], w[2], w[3]);
  }

  // We1^T chunks 0..5 in registers (48 VGPRs).
  uint4 afr[6][2];
#pragma unroll
  for (int c = 0; c < 6; ++c)
#pragma unroll
    for (int mt = 0; mt < 2; ++mt) {
      const int col = mt * 32 + n;
      const int kb = c * 16 + half * 8;
      unsigned w[4];
#pragma unroll
      for (int p = 0; p < 4; ++p)
        w[p] = f2bf_rne(We1[(kb + 2 * p) * 64 + col]) |
               (f2bf_rne(We1[(kb + 2 * p + 1) * 64 + col]) << 16);
      afr[c][mt] = make_uint4(w[0], w[1], w[2], w[3]);
    }
  // Bias chunk: only elem0 nonzero -> 2 regs.
  unsigned a12[2];
#pragma unroll
  for (int mt = 0; mt < 2; ++mt)
    a12[mt] = (half == 0) ? f2bf_rne(be1[mt * 32 + n]) : 0u;
  const uint4 b13u = make_uint4((half == 0) ? 0x00003F80u : 0u, 0u, 0u, 0u);
  const float be2v = be2[0];

  uint4* const buf = &gbuf[wave][0];
  int rbo[4];
#pragma unroll
  for (int c = 0; c < 4; ++c) rbo[c] = n * 8 + ((2 * c + half) ^ (n & 7));

  const int wid = blockIdx.x * 4 + wave;
  const int nw = gridDim.x * 4;  // 3072
  const int ntiles = N_EDGES / 32;
  const int last = ntiles - 1;
  const int2* pairs2 = (const int2*)pairs;

  // Weights visible to all waves; also drains vmem -> clean vmcnt state.
  __syncthreads();

  // Issue the 8 row-group gathers for one tile into buffer `dst`.
  auto issue_gathers = [&](uint4* dst, const int2* prs) {
#pragma unroll
    for (int k = 0; k < 4; ++k) {
      const AS1 unsigned* gu =
          (const AS1 unsigned*)(H + (size_t)prs[k].x * 64) + swzc * 4;
      const AS1 unsigned* gv =
          (const AS1 unsigned*)(H + (size_t)prs[k].y * 64) + swzc * 4;
      __builtin_amdgcn_global_load_lds(gu, (AS3 unsigned*)(dst + k * 64), 16,
                                       0, 0);
      __builtin_amdgcn_global_load_lds(
          gv, (AS3 unsigned*)(dst + 256 + k * 64), 16, 0, 0);
    }
  };

  // Prologue: gathers(t0) [8 outstanding after compiler drains pairs(t0)],
  // then pairs(t1) [4] => 12 outstanding at iter0 -> vmcnt(4) retires the 8.
  int2 pr[4];
  {
#pragma unroll
    for (int k = 0; k < 4; ++k) pr[k] = pairs2[wid * 32 + k * 8 + rowsel];
    issue_gathers(buf, pr);
    __builtin_amdgcn_sched_barrier(0);
    int t1 = wid + nw <= last ? wid + nw : last;
#pragma unroll
    for (int k = 0; k < 4; ++k) pr[k] = pairs2[t1 * 32 + k * 8 + rowsel];
  }

  // One tile: wait own gathers -> read rows to regs -> refill same buffer
  // for t+nw -> reload pr for t+2nw -> absdiff -> 26 MFMAs -> epilogue.
  auto body = [&](int tc, auto FIRST) {
    __builtin_amdgcn_sched_barrier(0);
    if constexpr (decltype(FIRST)::value)
      __builtin_amdgcn_s_waitcnt(0x0F74);  // vmcnt(4): iter0, no prior store
    else
      __builtin_amdgcn_s_waitcnt(0x0F75);  // vmcnt(5): steady state
    __builtin_amdgcn_sched_barrier(0);

    const int t = tc <= last ? tc : last;
    uint4 hu[4], hv[4];
#pragma unroll
    for (int c = 0; c < 4; ++c) {
      hu[c] = buf[rbo[c]];
      hv[c] = buf[256 + rbo[c]];
    }
    // Rows now (being) read to regs; fence completion, then reuse buffer.
    asm volatile("s_waitcnt lgkmcnt(0)" ::: "memory");
    __builtin_amdgcn_sched_barrier(0);
    issue_gathers(buf, pr);  // tile tc+nw, ~full tile of compute ahead
    __builtin_amdgcn_sched_barrier(0);  // pin: gathers before pairs loads
    {
      int tn = tc + 2 * nw <= last ? tc + 2 * nw : last;
#pragma unroll
      for (int k = 0; k < 4; ++k) pr[k] = pairs2[tn * 32 + k * 8 + rowsel];
    }

    uint4 ab[4];
#pragma unroll
    for (int c = 0; c < 4; ++c) {
      ab[c].x = absdiff_pack(hu[c].x, hv[c].x);
      ab[c].y = absdiff_pack(hu[c].y, hv[c].y);
      ab[c].z = absdiff_pack(hu[c].z, hv[c].z);
      ab[c].w = absdiff_pack(hu[c].w, hv[c].w);
    }

    f32x16 acc[2];
    acc[0] = (f32x16)(0.f);
    acc[1] = (f32x16)(0.f);
    // Chunks 0..3: hu, A from regs.
#pragma unroll
    for (int c = 0; c < 4; ++c) {
      const bf16x8 b = __builtin_bit_cast(bf16x8, hu[c]);
#pragma unroll
      for (int mt = 0; mt < 2; ++mt)
        acc[mt] = __builtin_amdgcn_mfma_f32_32x32x16_bf16(
            __builtin_bit_cast(bf16x8, afr[c][mt]), b, acc[mt], 0, 0, 0);
    }
    // Chunks 4..5: hv[0..1], A from regs.
#pragma unroll
    for (int c = 0; c < 2; ++c) {
      const bf16x8 b = __builtin_bit_cast(bf16x8, hv[c]);
#pragma unroll
      for (int mt = 0; mt < 2; ++mt)
        acc[mt] = __builtin_amdgcn_mfma_f32_32x32x16_bf16(
            __builtin_bit_cast(bf16x8, afr[4 + c][mt]), b, acc[mt], 0, 0, 0);
    }
    // Chunks 6..7: hv[2..3], A just-in-time from LDS.
#pragma unroll
    for (int c = 0; c < 2; ++c) {
      const bf16x8 b = __builtin_bit_cast(bf16x8, hv[2 + c]);
#pragma unroll
      for (int mt = 0; mt < 2; ++mt) {
        const uint4 a = lds_w6[c][mt][lane];
        acc[mt] = __builtin_amdgcn_mfma_f32_32x32x16_bf16(
            __builtin_bit_cast(bf16x8, a), b, acc[mt], 0, 0, 0);
      }
    }
    // Chunks 8..11: |hu-hv|, A just-in-time from LDS.
#pragma unroll
    for (int c = 0; c < 4; ++c) {
      const bf16x8 b = __builtin_bit_cast(bf16x8, ab[c]);
#pragma unroll
      for (int mt = 0; mt < 2; ++mt) {
        const uint4 a = lds_w6[2 + c][mt][lane];
        acc[mt] = __builtin_amdgcn_mfma_f32_32x32x16_bf16(
            __builtin_bit_cast(bf16x8, a), b, acc[mt], 0, 0, 0);
      }
    }
    // Chunk 12: bias.
#pragma unroll
    for (int mt = 0; mt < 2; ++mt)
      acc[mt] = __builtin_amdgcn_mfma_f32_32x32x16_bf16(
          __builtin_bit_cast(bf16x8, make_uint4(a12[mt], 0u, 0u, 0u)),
          __builtin_bit_cast(bf16x8, b13u), acc[mt], 0, 0, 0);

    // Epilogue: relu + We2 dot (We2 broadcast from LDS).
    // acc[mt][4g+q] -> hidden row o = mt*32 + q + 8g + 4*half.
    float s = 0.f;
#pragma unroll
    for (int mt = 0; mt < 2; ++mt)
#pragma unroll
      for (int g = 0; g < 4; ++g) {
        const float4 ew = *(const float4*)&lds_c[mt * 32 + g * 8 + 4 * half];
        s += fmaxf(acc[mt][4 * g + 0], 0.f) * ew.x;
        s += fmaxf(acc[mt][4 * g + 1], 0.f) * ew.y;
        s += fmaxf(acc[mt][4 * g + 2], 0.f) * ew.z;
        s += fmaxf(acc[mt][4 * g + 3], 0.f) * ew.w;
      }
    s += __shfl_xor(s, 32);
    if (half == 0) out[t * 32 + n] = s + be2v;
  };

  int t = wid;
  body(t, TrueTag{});
  for (t += nw; t < ntiles; t += nw) body(t, FalseTag{});
}

extern "C" void kernel_launch(void* const* d_in, const int* in_sizes, int n_in,
                              void* d_out, int out_size, void* d_ws,
                              size_t ws_size, hipStream_t stream) {
  const float* X = (const float*)d_in[0];
  const int* pairs = (const int*)d_in[1];
  const float* W1 = (const float*)d_in[2];
  const float* b1 = (const float*)d_in[3];
  const float* W2 = (const float*)d_in[4];
  const float* b2 = (const float*)d_in[5];
  const float* We1 = (const float*)d_in[6];
  const float* be1 = (const float*)d_in[7];
  const float* We2 = (const float*)d_in[8];
  const float* be2 = (const float*)d_in[9];
  float* out = (float*)d_out;
  unsigned short* H = (unsigned short*)d_ws;  // 100000*64 bf16 = 12.8 MB

  node_mfma_kernel<<<1024, 64, 0, stream>>>(X, W1, b1, W2, b2, H);
  // 44.3 KB LDS/block, ~160 regs/wave -> 3 blocks/CU, 12 waves/CU.
  // 768 blocks = exactly resident.
  edge_mlp_kernel<<<768, 256, 0, stream>>>(H, pairs, We1, be1, We2, be2, out);
}